// Round 1
// baseline (6613.338 us; speedup 1.0000x reference)
//
#include <hip/hip_runtime.h>
#include <hip/hip_bf16.h>
#include <math.h>

#define NL 6
#define DM 272
#define DS 64
#define DI 544
#define DTR 17
#define NSC 4
#define BB 4
#define LL 2048
#define MTOK (BB*LL)

__device__ __forceinline__ float sigmoidf_(float x){ return 1.0f/(1.0f+__expf(-x)); }

// ---------------- LayerNorm: one wave per token ----------------
__global__ __launch_bounds__(256) void ln_kernel(const float* __restrict__ X,
                          const float* __restrict__ w,
                          const float* __restrict__ b,
                          float* __restrict__ H)
{
    int wave = threadIdx.x >> 6;
    int lane = threadIdx.x & 63;
    int tok = blockIdx.x*4 + wave;
    const float* xr = X + (size_t)tok*DM;
    float v[5];
    float s=0.f, ss=0.f;
    #pragma unroll
    for (int j=0;j<5;++j){
        int idx = lane + j*64;
        float x = (idx < DM) ? xr[idx] : 0.f;
        v[j]=x; s+=x; ss+=x*x;
    }
    #pragma unroll
    for (int off=1; off<64; off<<=1){ s += __shfl_xor(s,off); ss += __shfl_xor(ss,off); }
    float mu  = s * (1.0f/DM);
    float var = ss*(1.0f/DM) - mu*mu;
    float inv = 1.0f/sqrtf(var + 1e-5f);
    float* hr = H + (size_t)tok*DM;
    #pragma unroll
    for (int j=0;j<5;++j){
        int idx = lane + j*64;
        if (idx<DM) hr[idx] = (v[j]-mu)*inv*w[idx] + b[idx];
    }
}

// ---------------- f32 GEMM: C[M,N] = A[M,K] @ W[N,K]^T (+ residual) ----------------
// tile 64x64, BK=16, 256 threads, 4x4 micro-tile. M%64==0, K%16==0 required; N guarded.
template<bool RESID>
__global__ __launch_bounds__(256) void gemm_tn(const float* __restrict__ A, int lda,
                        const float* __restrict__ W,
                        float* __restrict__ C, int ldc,
                        const float* __restrict__ R, int ldr,
                        int N, int K)
{
    __shared__ float As[16][68];
    __shared__ float Bs[16][68];
    int bm = blockIdx.x*64, bn = blockIdx.y*64;
    int tid = threadIdx.x;
    int tn = tid & 15, tm = tid >> 4;
    int lrow = tid >> 2, lkq = (tid & 3)*4;
    float acc[4][4] = {};
    for (int k0=0; k0<K; k0+=16){
        float4 va = *(const float4*)(A + (size_t)(bm+lrow)*lda + k0 + lkq);
        As[lkq+0][lrow]=va.x; As[lkq+1][lrow]=va.y; As[lkq+2][lrow]=va.z; As[lkq+3][lrow]=va.w;
        int wr = bn + lrow;
        float4 vb = make_float4(0.f,0.f,0.f,0.f);
        if (wr < N) vb = *(const float4*)(W + (size_t)wr*K + k0 + lkq);
        Bs[lkq+0][lrow]=vb.x; Bs[lkq+1][lrow]=vb.y; Bs[lkq+2][lrow]=vb.z; Bs[lkq+3][lrow]=vb.w;
        __syncthreads();
        #pragma unroll
        for (int k=0;k<16;++k){
            float4 av = *(const float4*)&As[k][tm*4];
            float4 bv = *(const float4*)&Bs[k][tn*4];
            float a[4]={av.x,av.y,av.z,av.w};
            float bb[4]={bv.x,bv.y,bv.z,bv.w};
            #pragma unroll
            for (int i=0;i<4;++i)
                #pragma unroll
                for (int j=0;j<4;++j)
                    acc[i][j] = fmaf(a[i], bb[j], acc[i][j]);
        }
        __syncthreads();
    }
    #pragma unroll
    for (int i=0;i<4;++i){
        int row = bm + tm*4 + i;
        #pragma unroll
        for (int j=0;j<4;++j){
            int col = bn + tn*4 + j;
            if (col < N){
                float v = acc[i][j];
                if (RESID) v += R[(size_t)row*ldr + col];
                C[(size_t)row*ldc + col] = v;
            }
        }
    }
}

// ---------------- depthwise causal conv (k=4) + SiLU ----------------
__global__ __launch_bounds__(256) void conv_silu_kernel(const float* __restrict__ XZ,
                                 const float* __restrict__ cw,
                                 const float* __restrict__ cb,
                                 float* __restrict__ XC)
{
    int idx = blockIdx.x*256 + threadIdx.x;   // over MTOK*DI
    int d  = idx % DI;
    int tg = idx / DI;
    int t  = tg % LL;
    float acc = cb[d];
    const float* cwd = cw + d*4;
    #pragma unroll
    for (int k=0;k<4;++k){
        int tt = t - 3 + k;
        if (tt >= 0)
            acc = fmaf(XZ[(size_t)(tg - 3 + k)*(2*DI) + d], cwd[k], acc);
    }
    XC[idx] = acc * sigmoidf_(acc);
}

// ---------------- dt_proj (K=17) + softplus ----------------
__global__ __launch_bounds__(256) void dt_kernel(const float* __restrict__ DBLb,
                          const float* __restrict__ Wdt,
                          const float* __restrict__ bdt,
                          float* __restrict__ DEL)
{
    int idx = blockIdx.x*256 + threadIdx.x;   // over MTOK*DI
    int d  = idx % DI;
    int tg = idx / DI;
    const float* dtv = DBLb + (size_t)tg*145;
    const float* wr  = Wdt + d*DTR;
    float s = bdt[d];
    #pragma unroll
    for (int r=0;r<DTR;++r) s = fmaf(dtv[r], wr[r], s);
    DEL[idx] = (s > 20.f) ? s : log1pf(__expf(s));
}

// ---------------- selective scan: one wave per (b,d), lane = n ----------------
// y_final = (scan_y + u*Dd) * silu(z), written into the xi slot of XZ.
__global__ __launch_bounds__(256) void scan_kernel(const float* __restrict__ DEL,
                            const float* __restrict__ XC,
                            const float* __restrict__ DBLb,
                            float* __restrict__ XZ,
                            const float* __restrict__ A_log,
                            const float* __restrict__ Dskip)
{
    int wave = threadIdx.x >> 6, lane = threadIdx.x & 63;
    int gc = blockIdx.x*4 + wave;          // 0..BB*DI-1
    int b = gc / DI, d = gc - b*DI;
    float Aval = -__expf(A_log[d*DS + lane]);
    float Dd = Dskip[d];
    float h = 0.f;
    size_t tokBase = (size_t)b*LL;
    // preload t=0
    float delta = DEL[tokBase*DI + d];
    float u     = XC[tokBase*DI + d];
    float Bv    = DBLb[tokBase*145 + 17 + lane];
    float Cv    = DBLb[tokBase*145 + 81 + lane];
    float z     = XZ[tokBase*(2*DI) + DI + d];
    for (int t=0; t<LL; ++t){
        size_t cur = tokBase + t;
        float deltaN=0.f, uN=0.f, BvN=0.f, CvN=0.f, zN=0.f;
        if (t+1 < LL){
            size_t nx = cur + 1;
            deltaN = DEL[nx*DI + d];
            uN     = XC[nx*DI + d];
            BvN    = DBLb[nx*145 + 17 + lane];
            CvN    = DBLb[nx*145 + 81 + lane];
            zN     = XZ[nx*(2*DI) + DI + d];
        }
        float e = __expf(delta*Aval);
        h = fmaf(e, h, delta*u*Bv);
        float p = h*Cv;
        #pragma unroll
        for (int off=1; off<64; off<<=1) p += __shfl_xor(p, off);
        if (lane == 0){
            float y = p + u*Dd;
            XZ[cur*(2*DI) + d] = y * z * sigmoidf_(z);
        }
        delta=deltaN; u=uN; Bv=BvN; Cv=CvN; z=zN;
    }
}

// ---------------- mean-pool + regression head ----------------
__global__ __launch_bounds__(256) void head_kernel(const float* __restrict__ X,
                            const float* __restrict__ reg_w,
                            const float* __restrict__ reg_b,
                            float* __restrict__ out)
{
    __shared__ float feat[DM];
    int b = blockIdx.x, tid = threadIdx.x;
    for (int dm = tid; dm < DM; dm += 256){
        float s = 0.f;
        const float* base = X + ((size_t)b*LL)*DM + dm;
        #pragma unroll 8
        for (int l=0;l<LL;++l) s += base[(size_t)l*DM];
        float f = s * (1.0f/LL);
        feat[dm] = f;
        out[16 + b*DM + dm] = f;
    }
    __syncthreads();
    if (tid < NSC){
        float s = reg_b[tid];
        const float* wr = reg_w + tid*DM;
        for (int k=0;k<DM;++k) s = fmaf(feat[k], wr[k], s);
        out[b*NSC + tid] = s;
    }
}

extern "C" void kernel_launch(void* const* d_in, const int* in_sizes, int n_in,
                              void* d_out, int out_size, void* d_ws, size_t ws_size,
                              hipStream_t stream)
{
    const float* x_in  = (const float*)d_in[0];
    const float* ln_w  = (const float*)d_in[1];
    const float* ln_b  = (const float*)d_in[2];
    const float* Wi    = (const float*)d_in[3];
    const float* cw    = (const float*)d_in[4];
    const float* cb    = (const float*)d_in[5];
    const float* Wx    = (const float*)d_in[6];
    const float* Wdt   = (const float*)d_in[7];
    const float* bdt   = (const float*)d_in[8];
    const float* A_log = (const float*)d_in[9];
    const float* Dd    = (const float*)d_in[10];
    const float* Wo    = (const float*)d_in[11];
    const float* regw  = (const float*)d_in[12];
    const float* regb  = (const float*)d_in[13];
    float* out = (float*)d_out;

    float* ws   = (float*)d_ws;
    float* H    = ws;                          // 8192*272
    float* XZ   = H    + (size_t)MTOK*DM;      // 8192*1088 (xi|z, y overwrites xi)
    float* XC   = XZ   + (size_t)MTOK*2*DI;    // 8192*544
    float* DBLb = XC   + (size_t)MTOK*DI;      // 8192*145
    float* DELb = DBLb + (size_t)MTOK*145;     // 8192*544
    float* Xb   = DELb + (size_t)MTOK*DI;      // 8192*272 residual stream

    hipMemcpyAsync(Xb, x_in, sizeof(float)*(size_t)MTOK*DM, hipMemcpyDeviceToDevice, stream);

    for (int l=0; l<NL; ++l){
        ln_kernel<<<MTOK/4, 256, 0, stream>>>(Xb, ln_w + l*DM, ln_b + l*DM, H);
        gemm_tn<false><<<dim3(MTOK/64, (2*DI+63)/64), 256, 0, stream>>>(
            H, DM, Wi + (size_t)l*2*DI*DM, XZ, 2*DI, nullptr, 0, 2*DI, DM);
        conv_silu_kernel<<<(MTOK*DI)/256, 256, 0, stream>>>(XZ, cw + l*DI*4, cb + l*DI, XC);
        gemm_tn<false><<<dim3(MTOK/64, (145+63)/64), 256, 0, stream>>>(
            XC, DI, Wx + (size_t)l*145*DI, DBLb, 145, nullptr, 0, 145, DI);
        dt_kernel<<<(MTOK*DI)/256, 256, 0, stream>>>(DBLb, Wdt + (size_t)l*DI*DTR, bdt + l*DI, DELb);
        scan_kernel<<<(BB*DI)/4, 256, 0, stream>>>(DELb, XC, DBLb, XZ,
                                                   A_log + (size_t)l*DI*DS, Dd + l*DI);
        gemm_tn<true><<<dim3(MTOK/64, (DM+63)/64), 256, 0, stream>>>(
            XZ, 2*DI, Wo + (size_t)l*DM*DI, Xb, DM, Xb, DM, DM, DI);
    }
    head_kernel<<<BB, 256, 0, stream>>>(Xb, regw, regb, out);
}

// Round 3
// 2958.617 us; speedup vs baseline: 2.2353x; 2.2353x over previous
//
#include <hip/hip_runtime.h>
#include <hip/hip_bf16.h>
#include <math.h>

#define NL 6
#define DM 272
#define DS 64
#define DI 544
#define DTR 17
#define NSC 4
#define BB 4
#define LL 2048
#define MTOK (BB*LL)
#define TCH 128
#define CH  (LL/TCH)   // 16 chunks

__device__ __forceinline__ float sigmoidf_(float x){ return 1.0f/(1.0f+__expf(-x)); }
__device__ __forceinline__ float rlf(float x, int s){ return __int_as_float(__builtin_amdgcn_readlane(__float_as_int(x), s)); }

#define DPPADD(x, ctrl) x += __int_as_float(__builtin_amdgcn_update_dpp(0, __float_as_int(x), ctrl, 0xf, 0xf, true))
// full-wave64 sum; result valid in lane 63
__device__ __forceinline__ float wsum64(float x){
    DPPADD(x, 0x111); // row_shr:1
    DPPADD(x, 0x112); // row_shr:2
    DPPADD(x, 0x114); // row_shr:4
    DPPADD(x, 0x118); // row_shr:8
    DPPADD(x, 0x142); // row_bcast:15
    DPPADD(x, 0x143); // row_bcast:31
    return x;
}

// ---------------- LayerNorm: one wave per token ----------------
__global__ __launch_bounds__(256) void ln_kernel(const float* __restrict__ X,
                          const float* __restrict__ w,
                          const float* __restrict__ b,
                          float* __restrict__ H)
{
    int wave = threadIdx.x >> 6;
    int lane = threadIdx.x & 63;
    int tok = blockIdx.x*4 + wave;
    const float* xr = X + (size_t)tok*DM;
    float v[5];
    float s=0.f, ss=0.f;
    #pragma unroll
    for (int j=0;j<5;++j){
        int idx = lane + j*64;
        float x = (idx < DM) ? xr[idx] : 0.f;
        v[j]=x; s+=x; ss+=x*x;
    }
    #pragma unroll
    for (int off=1; off<64; off<<=1){ s += __shfl_xor(s,off); ss += __shfl_xor(ss,off); }
    float mu  = s * (1.0f/DM);
    float var = ss*(1.0f/DM) - mu*mu;
    float inv = 1.0f/sqrtf(var + 1e-5f);
    float* hr = H + (size_t)tok*DM;
    #pragma unroll
    for (int j=0;j<5;++j){
        int idx = lane + j*64;
        if (idx<DM) hr[idx] = (v[j]-mu)*inv*w[idx] + b[idx];
    }
}

// ---------------- f32 GEMM: C[M,N] = A[M,K] @ W[N,K]^T (+ residual) ----------------
template<bool RESID>
__global__ __launch_bounds__(256) void gemm_tn(const float* __restrict__ A, int lda,
                        const float* __restrict__ W,
                        float* __restrict__ C, int ldc,
                        const float* __restrict__ R, int ldr,
                        int N, int K)
{
    __shared__ float As[16][68];
    __shared__ float Bs[16][68];
    int bm = blockIdx.x*64, bn = blockIdx.y*64;
    int tid = threadIdx.x;
    int tn = tid & 15, tm = tid >> 4;
    int lrow = tid >> 2, lkq = (tid & 3)*4;
    float acc[4][4] = {};
    for (int k0=0; k0<K; k0+=16){
        float4 va = *(const float4*)(A + (size_t)(bm+lrow)*lda + k0 + lkq);
        As[lkq+0][lrow]=va.x; As[lkq+1][lrow]=va.y; As[lkq+2][lrow]=va.z; As[lkq+3][lrow]=va.w;
        int wr = bn + lrow;
        float4 vb = make_float4(0.f,0.f,0.f,0.f);
        if (wr < N) vb = *(const float4*)(W + (size_t)wr*K + k0 + lkq);
        Bs[lkq+0][lrow]=vb.x; Bs[lkq+1][lrow]=vb.y; Bs[lkq+2][lrow]=vb.z; Bs[lkq+3][lrow]=vb.w;
        __syncthreads();
        #pragma unroll
        for (int k=0;k<16;++k){
            float4 av = *(const float4*)&As[k][tm*4];
            float4 bv = *(const float4*)&Bs[k][tn*4];
            float a[4]={av.x,av.y,av.z,av.w};
            float bb[4]={bv.x,bv.y,bv.z,bv.w};
            #pragma unroll
            for (int i=0;i<4;++i)
                #pragma unroll
                for (int j=0;j<4;++j)
                    acc[i][j] = fmaf(a[i], bb[j], acc[i][j]);
        }
        __syncthreads();
    }
    #pragma unroll
    for (int i=0;i<4;++i){
        int row = bm + tm*4 + i;
        #pragma unroll
        for (int j=0;j<4;++j){
            int col = bn + tn*4 + j;
            if (col < N){
                float v = acc[i][j];
                if (RESID) v += R[(size_t)row*ldr + col];
                C[(size_t)row*ldc + col] = v;
            }
        }
    }
}

// ---------------- depthwise causal conv (k=4) + SiLU ----------------
__global__ __launch_bounds__(256) void conv_silu_kernel(const float* __restrict__ XZ,
                                 const float* __restrict__ cw,
                                 const float* __restrict__ cb,
                                 float* __restrict__ XC)
{
    int idx = blockIdx.x*256 + threadIdx.x;   // over MTOK*DI
    int d  = idx % DI;
    int tg = idx / DI;
    int t  = tg % LL;
    float acc = cb[d];
    const float* cwd = cw + d*4;
    #pragma unroll
    for (int k=0;k<4;++k){
        int tt = t - 3 + k;
        if (tt >= 0)
            acc = fmaf(XZ[(size_t)(tg - 3 + k)*(2*DI) + d], cwd[k], acc);
    }
    XC[idx] = acc * sigmoidf_(acc);
}

// ---------------- dt_proj (K=17) + softplus ----------------
__global__ __launch_bounds__(256) void dt_kernel(const float* __restrict__ DBLb,
                          const float* __restrict__ Wdt,
                          const float* __restrict__ bdt,
                          float* __restrict__ DEL)
{
    int idx = blockIdx.x*256 + threadIdx.x;   // over MTOK*DI
    int d  = idx % DI;
    int tg = idx / DI;
    const float* dtv = DBLb + (size_t)tg*145;
    const float* wr  = Wdt + d*DTR;
    float s = bdt[d];
    #pragma unroll
    for (int r=0;r<DTR;++r) s = fmaf(dtv[r], wr[r], s);
    DEL[idx] = (s > 20.f) ? s : log1pf(__expf(s));
}

// ---------------- scan phase A: per-chunk q and sum(delta), h_in = 0 ----------------
__global__ __launch_bounds__(256) void scan_a(const float* __restrict__ DEL,
                       const float* __restrict__ XC,
                       const float* __restrict__ DBLb,
                       const float* __restrict__ A_log,
                       float* __restrict__ Q,
                       float* __restrict__ S)
{
    int wave = threadIdx.x >> 6, lane = threadIdx.x & 63;
    int wid = blockIdx.x*4 + wave;           // (b, c, d) with d fastest
    int d = wid % DI;
    int c = (wid / DI) % CH;
    int b = wid / (DI*CH);
    float Aval = -__expf(A_log[d*DS + lane]);
    size_t tok0 = (size_t)b*LL + (size_t)c*TCH;
    float dl0 = DEL[(tok0 + lane)*DI + d];
    float dl1 = DEL[(tok0 + 64 + lane)*DI + d];
    float ul0 = XC[(tok0 + lane)*DI + d];
    float ul1 = XC[(tok0 + 64 + lane)*DI + d];
    float du0 = dl0*ul0, du1 = dl1*ul1;
    const float* p = DBLb + tok0*145;
    float h = 0.f;
    #pragma unroll
    for (int s=0; s<64; ++s){
        float Bv = p[17+lane];
        float sd = rlf(dl0, s), sdu = rlf(du0, s);
        h = fmaf(__expf(sd*Aval), h, sdu*Bv);
        p += 145;
    }
    #pragma unroll
    for (int s=0; s<64; ++s){
        float Bv = p[17+lane];
        float sd = rlf(dl1, s), sdu = rlf(du1, s);
        h = fmaf(__expf(sd*Aval), h, sdu*Bv);
        p += 145;
    }
    size_t qidx = (size_t)(b*DI + d)*CH + c;
    Q[qidx*64 + lane] = h;
    float Ssum = wsum64(dl0 + dl1);
    if (lane == 63) S[qidx] = Ssum;
}

// ---------------- scan phase B: sequential chunk combine, in-place h_in into Q ----------------
__global__ __launch_bounds__(256) void scan_b(float* __restrict__ Q,
                       const float* __restrict__ S,
                       const float* __restrict__ A_log)
{
    int tid = threadIdx.x;
    int n = tid & 63;
    int dq = tid >> 6;                        // 4 d per block
    int b = blockIdx.x / (DI/4);
    int d = (blockIdx.x % (DI/4))*4 + dq;
    float Aval = -__expf(A_log[d*DS + n]);
    float h = 0.f;
    size_t base = (size_t)(b*DI + d)*CH;
    for (int c=0; c<CH; ++c){
        size_t idx = base + c;
        float q  = Q[idx*64 + n];
        float Sv = S[idx];
        Q[idx*64 + n] = h;                    // h_in for chunk c
        h = fmaf(__expf(Aval*Sv), h, q);
    }
}

// ---------------- scan phase C: re-scan chunk from h_in, emit gated y ----------------
__global__ __launch_bounds__(256) void scan_c(const float* __restrict__ DEL,
                       const float* __restrict__ XC,
                       const float* __restrict__ DBLb,
                       float* __restrict__ XZ,
                       const float* __restrict__ A_log,
                       const float* __restrict__ Dskip,
                       const float* __restrict__ Q)
{
    int wave = threadIdx.x >> 6, lane = threadIdx.x & 63;
    int wid = blockIdx.x*4 + wave;
    int d = wid % DI;
    int c = (wid / DI) % CH;
    int b = wid / (DI*CH);
    float Aval = -__expf(A_log[d*DS + lane]);
    float Dd = Dskip[d];
    size_t tok0 = (size_t)b*LL + (size_t)c*TCH;
    size_t qidx = (size_t)(b*DI + d)*CH + c;
    float h = Q[qidx*64 + lane];
    float dl0 = DEL[(tok0 + lane)*DI + d];
    float dl1 = DEL[(tok0 + 64 + lane)*DI + d];
    float ul0 = XC[(tok0 + lane)*DI + d];
    float ul1 = XC[(tok0 + 64 + lane)*DI + d];
    float zl0 = XZ[(tok0 + lane)*(2*DI) + DI + d];
    float zl1 = XZ[(tok0 + 64 + lane)*(2*DI) + DI + d];
    float du0 = dl0*ul0, du1 = dl1*ul1;
    const float* p = DBLb + tok0*145;
    float y0 = 0.f, y1 = 0.f;
    #pragma unroll
    for (int s=0; s<64; ++s){
        float Bv = p[17+lane];
        float Cv = p[81+lane];
        float sd = rlf(dl0, s), sdu = rlf(du0, s);
        h = fmaf(__expf(sd*Aval), h, sdu*Bv);
        float pp = wsum64(h*Cv);
        float pb = rlf(pp, 63);
        if (lane == s) y0 = pb;
        p += 145;
    }
    #pragma unroll
    for (int s=0; s<64; ++s){
        float Bv = p[17+lane];
        float Cv = p[81+lane];
        float sd = rlf(dl1, s), sdu = rlf(du1, s);
        h = fmaf(__expf(sd*Aval), h, sdu*Bv);
        float pp = wsum64(h*Cv);
        float pb = rlf(pp, 63);
        if (lane == s) y1 = pb;
        p += 145;
    }
    y0 = (y0 + ul0*Dd) * (zl0 * sigmoidf_(zl0));
    y1 = (y1 + ul1*Dd) * (zl1 * sigmoidf_(zl1));
    XZ[(tok0 + lane)*(2*DI) + d]      = y0;
    XZ[(tok0 + 64 + lane)*(2*DI) + d] = y1;
}

// ---------------- mean-pool + regression head ----------------
__global__ __launch_bounds__(256) void head_kernel(const float* __restrict__ X,
                            const float* __restrict__ reg_w,
                            const float* __restrict__ reg_b,
                            float* __restrict__ out)
{
    __shared__ float feat[DM];
    int b = blockIdx.x, tid = threadIdx.x;
    for (int dm = tid; dm < DM; dm += 256){
        float s = 0.f;
        const float* base = X + ((size_t)b*LL)*DM + dm;
        #pragma unroll 8
        for (int l=0;l<LL;++l) s += base[(size_t)l*DM];
        float f = s * (1.0f/LL);
        feat[dm] = f;
        out[16 + b*DM + dm] = f;
    }
    __syncthreads();
    if (tid < NSC){
        float s = reg_b[tid];
        const float* wr = reg_w + tid*DM;
        for (int k=0;k<DM;++k) s = fmaf(feat[k], wr[k], s);
        out[b*NSC + tid] = s;
    }
}

extern "C" void kernel_launch(void* const* d_in, const int* in_sizes, int n_in,
                              void* d_out, int out_size, void* d_ws, size_t ws_size,
                              hipStream_t stream)
{
    const float* x_in  = (const float*)d_in[0];
    const float* ln_w  = (const float*)d_in[1];
    const float* ln_b  = (const float*)d_in[2];
    const float* Wi    = (const float*)d_in[3];
    const float* cw    = (const float*)d_in[4];
    const float* cb    = (const float*)d_in[5];
    const float* Wx    = (const float*)d_in[6];
    const float* Wdt   = (const float*)d_in[7];
    const float* bdt   = (const float*)d_in[8];
    const float* A_log = (const float*)d_in[9];
    const float* Dd    = (const float*)d_in[10];
    const float* Wo    = (const float*)d_in[11];
    const float* regw  = (const float*)d_in[12];
    const float* regb  = (const float*)d_in[13];
    float* out = (float*)d_out;

    float* ws   = (float*)d_ws;
    float* H    = ws;                          // 8192*272 ; Q overlays (exactly equal size)
    float* XZ   = H    + (size_t)MTOK*DM;      // 8192*1088 (xi|z, y overwrites xi)
    float* XC   = XZ   + (size_t)MTOK*2*DI;    // 8192*544
    float* DBLb = XC   + (size_t)MTOK*DI;      // 8192*145
    float* DELb = DBLb + (size_t)MTOK*145;     // 8192*544
    float* Xb   = DELb + (size_t)MTOK*DI;      // 8192*272 residual stream
    float* Sbuf = Xb   + (size_t)MTOK*DM;      // BB*DI*CH = 34816 floats
    float* Q    = H;                           // BB*DI*CH*DS floats == MTOK*DM exactly

    (void)hipMemcpyAsync(Xb, x_in, sizeof(float)*(size_t)MTOK*DM, hipMemcpyDeviceToDevice, stream);

    for (int l=0; l<NL; ++l){
        ln_kernel<<<MTOK/4, 256, 0, stream>>>(Xb, ln_w + l*DM, ln_b + l*DM, H);
        gemm_tn<false><<<dim3(MTOK/64, (2*DI+63)/64), 256, 0, stream>>>(
            H, DM, Wi + (size_t)l*2*DI*DM, XZ, 2*DI, nullptr, 0, 2*DI, DM);
        conv_silu_kernel<<<(MTOK*DI)/256, 256, 0, stream>>>(XZ, cw + l*DI*4, cb + l*DI, XC);
        gemm_tn<false><<<dim3(MTOK/64, (145+63)/64), 256, 0, stream>>>(
            XC, DI, Wx + (size_t)l*145*DI, DBLb, 145, nullptr, 0, 145, DI);
        dt_kernel<<<(MTOK*DI)/256, 256, 0, stream>>>(DBLb, Wdt + (size_t)l*DI*DTR, bdt + l*DI, DELb);
        scan_a<<<(BB*DI*CH)/4, 256, 0, stream>>>(DELb, XC, DBLb, A_log + (size_t)l*DI*DS, Q, Sbuf);
        scan_b<<<BB*(DI/4), 256, 0, stream>>>(Q, Sbuf, A_log + (size_t)l*DI*DS);
        scan_c<<<(BB*DI*CH)/4, 256, 0, stream>>>(DELb, XC, DBLb, XZ,
                                                 A_log + (size_t)l*DI*DS, Dd + l*DI, Q);
        gemm_tn<true><<<dim3(MTOK/64, (DM+63)/64), 256, 0, stream>>>(
            XZ, 2*DI, Wo + (size_t)l*DM*DI, Xb, DM, Xb, DM, DM, DI);
    }
    head_kernel<<<BB, 256, 0, stream>>>(Xb, regw, regb, out);
}